// Round 3
// baseline (1291.341 us; speedup 1.0000x reference)
//
#include <hip/hip_runtime.h>
#include <stdint.h>

#define L_SZ 110
#define D_SZ 512
#define OUT_W 110
#define A_STRIDE 520   // bf16 elems per LDS A row (fallback kernel)
#define C_STRIDE 136
#define A_ROWS 112
#define ATT_ROWS 112
#define TR_STRIDE 72   // 64 + 8 pad, keeps 16B alignment

typedef __attribute__((ext_vector_type(8))) __bf16 bf16x8;
typedef __attribute__((ext_vector_type(4))) __bf16 bf16x4;
typedef __attribute__((ext_vector_type(4))) float f32x4;

// Convert W (512x512 fp32, row-major [d][e]) to bf16 in workspace.
__global__ __launch_bounds__(256) void wconv_kernel(const float* __restrict__ W,
                                                    __bf16* __restrict__ wbf) {
    int idx = blockIdx.x * 256 + threadIdx.x;
    float4 w = ((const float4*)W)[idx];
    bf16x4 o;
    o[0] = (__bf16)w.x; o[1] = (__bf16)w.y; o[2] = (__bf16)w.z; o[3] = (__bf16)w.w;
    ((bf16x4*)wbf)[idx] = o;
}

// ---------------- K1: att[b,l,d] = sum_e W[d,e]*nf[b,l,e], barrier-free tiled GEMM ----
// grid (4, B): blockIdx.x = rg*2+cg ; rg = 64-row group, cg = 256-col group.
// 256 threads / 4 waves; wave w owns cols [cg*256 + w*64, +64): 4x4 16x16 tiles.
__global__ __launch_bounds__(256, 3) void att_gemm2_kernel(
    const float* __restrict__ nf, const __bf16* __restrict__ wbf,
    const int* __restrict__ tlenp, __bf16* __restrict__ attws)
{
    __shared__ __bf16 tr[4][64 * TR_STRIDE];   // wave-private transpose staging (no barriers)

    const int b   = blockIdx.y;
    const int rg  = blockIdx.x >> 1;
    const int cg  = blockIdx.x & 1;
    const int tid = threadIdx.x;
    const int lane = tid & 63;
    const int wave = tid >> 6;
    const int l15 = lane & 15;
    const int quad = lane >> 4;

    int len = tlenp[b];
    if (len > L_SZ) len = L_SZ;
    if (len < 1) len = 1;
    const int T = (len + 15) >> 4;

    int nmt = T - rg * 4;
    if (nmt <= 0) return;
    if (nmt > 4) nmt = 4;

    const float* nfb = nf + (size_t)b * (L_SZ * D_SZ);
    const int rowbase = rg * 64;
    const int nbase = cg * 256 + wave * 64;

    const f32x4 fz = {0.f, 0.f, 0.f, 0.f};
    f32x4 acc[4][4];
    #pragma unroll
    for (int mi = 0; mi < 4; ++mi)
        #pragma unroll
        for (int ni = 0; ni < 4; ++ni) acc[mi][ni] = fz;

    const float4 zf4 = {0.f, 0.f, 0.f, 0.f};

    for (int k0 = 0; k0 < D_SZ; k0 += 32) {
        bf16x8 bfr[4];
        #pragma unroll
        for (int ni = 0; ni < 4; ++ni) {
            int d = nbase + (ni << 4) + l15;
            bfr[ni] = *(const bf16x8*)&wbf[(size_t)d * D_SZ + k0 + (quad << 3)];
        }
        bf16x8 afr[4];
        #pragma unroll
        for (int mi = 0; mi < 4; ++mi) {
            if (mi < nmt) {
                int row = rowbase + (mi << 4) + l15;
                bool ok = (row < len);
                const float* ap = &nfb[(size_t)row * D_SZ + k0 + (quad << 3)];
                float4 a0 = ok ? *(const float4*)ap : zf4;
                float4 a1 = ok ? *(const float4*)(ap + 4) : zf4;
                bf16x8 af;
                af[0] = (__bf16)a0.x; af[1] = (__bf16)a0.y;
                af[2] = (__bf16)a0.z; af[3] = (__bf16)a0.w;
                af[4] = (__bf16)a1.x; af[5] = (__bf16)a1.y;
                af[6] = (__bf16)a1.z; af[7] = (__bf16)a1.w;
                afr[mi] = af;
            }
        }
        #pragma unroll
        for (int mi = 0; mi < 4; ++mi)
            if (mi < nmt)
                #pragma unroll
                for (int ni = 0; ni < 4; ++ni)
                    acc[mi][ni] = __builtin_amdgcn_mfma_f32_16x16x32_bf16(
                        afr[mi], bfr[ni], acc[mi][ni], 0, 0, 0);
    }

    // epilogue: wave-private LDS transpose (C/D layout -> row-major), coalesced stores
    __bf16* tw = tr[wave];
    #pragma unroll
    for (int mi = 0; mi < 4; ++mi) {
        if (mi < nmt) {
            int rb = (mi << 4) + (quad << 2);
            #pragma unroll
            for (int ni = 0; ni < 4; ++ni) {
                int c = (ni << 4) + l15;
                #pragma unroll
                for (int r = 0; r < 4; ++r)
                    tw[(rb + r) * TR_STRIDE + c] = (__bf16)acc[mi][ni][r];
            }
        }
    }
    const int nrows = nmt << 4;
    #pragma unroll
    for (int p = 0; p < 8; ++p) {
        int idx = (p << 6) + lane;
        int row = idx >> 3;          // 0..63
        int c8  = idx & 7;
        if (row < nrows) {
            bf16x8 v = *(const bf16x8*)&tw[row * TR_STRIDE + (c8 << 3)];
            *(bf16x8*)&attws[((size_t)b * ATT_ROWS + rowbase + row) * D_SZ + nbase + (c8 << 3)] = v;
        }
    }
}

// ---------------- K2: banded scores + masked softmax, no LDS, no barriers ----------------
__global__ __launch_bounds__(256) void band_kernel(
    const float* __restrict__ nf, const __bf16* __restrict__ attws,
    const int* __restrict__ tlenp, float* __restrict__ out)
{
    const int b = blockIdx.x;
    const int tid = threadIdx.x;
    const int lane = tid & 63;
    const int wave = tid >> 6;
    const int l15 = lane & 15;
    const int quad = lane >> 4;

    int len = tlenp[b];
    if (len > L_SZ) len = L_SZ;
    if (len < 1) len = 1;
    const int T = (len + 15) >> 4;

    const float* nfb = nf + (size_t)b * (L_SZ * D_SZ);
    float* outb = out + (size_t)b * (L_SZ * OUT_W);

    const f32x4 fz = {0.f, 0.f, 0.f, 0.f};
    f32x4 accS[2][3];
    #pragma unroll
    for (int i = 0; i < 2; ++i)
        #pragma unroll
        for (int t = 0; t < 3; ++t) accS[i][t] = fz;

    #pragma unroll
    for (int i = 0; i < 2; ++i) {
        const int tj = wave + (i << 2);
        if (tj < T) {
            int jr = (tj << 4) + l15;
            if (jr > L_SZ - 1) jr = L_SZ - 1;   // keep in-bounds; rows >= len discarded later
            const float* ap0 = &nfb[(size_t)jr * D_SZ];
            for (int k0 = 0; k0 < D_SZ; k0 += 32) {
                float4 a0 = *(const float4*)(ap0 + k0 + (quad << 3));
                float4 a1 = *(const float4*)(ap0 + k0 + (quad << 3) + 4);
                bf16x8 af;
                af[0] = (__bf16)a0.x; af[1] = (__bf16)a0.y;
                af[2] = (__bf16)a0.z; af[3] = (__bf16)a0.w;
                af[4] = (__bf16)a1.x; af[5] = (__bf16)a1.y;
                af[6] = (__bf16)a1.z; af[7] = (__bf16)a1.w;
                #pragma unroll
                for (int t = 0; t < 3; ++t) {
                    int tl = tj - 1 + t;
                    if (tl >= 0 && tl < T) {
                        bf16x8 bfr = *(const bf16x8*)&attws[((size_t)b * ATT_ROWS + (tl << 4) + l15) * D_SZ + k0 + (quad << 3)];
                        accS[i][t] = __builtin_amdgcn_mfma_f32_16x16x32_bf16(
                            af, bfr, accS[i][t], 0, 0, 0);
                    }
                }
            }
        }
    }

    #pragma unroll
    for (int i = 0; i < 2; ++i) {
        int tj = wave + 4 * i;
        if (tj >= T) continue;           // wave-uniform
        #pragma unroll
        for (int r = 0; r < 4; ++r) {
            int j = tj * 16 + quad * 4 + r;
            float v[3]; bool mk[3];
            float vmax = -3.0e38f;
            #pragma unroll
            for (int t = 0; t < 3; ++t) {
                int tl = tj - 1 + t;
                int l = tl * 16 + l15;
                bool in = (tl >= 0) && (tl < T) && (j < len) && (l < len)
                          && (l >= j - 10) && (l <= j + 10);
                float val = in ? accS[i][t][r] : -3.0e38f;
                mk[t] = in; v[t] = val;
                vmax = fmaxf(vmax, val);
            }
            #pragma unroll
            for (int s = 1; s < 16; s <<= 1)
                vmax = fmaxf(vmax, __shfl_xor(vmax, s, 16));
            float e[3]; float esum = 0.f;
            #pragma unroll
            for (int t = 0; t < 3; ++t) {
                e[t] = mk[t] ? __expf(v[t] - vmax) : 0.f;
                esum += e[t];
            }
            #pragma unroll
            for (int s = 1; s < 16; s <<= 1)
                esum += __shfl_xor(esum, s, 16);
            float inv = (esum > 0.f) ? (1.0f / esum) : 0.f;
            if (j < OUT_W) {
                #pragma unroll
                for (int t = 0; t < 3; ++t) {
                    int tl = tj - 1 + t;
                    if (tl >= 0 && tl < T) {
                        int l = tl * 16 + l15;
                        if (l < OUT_W) outb[(size_t)j * OUT_W + l] = e[t] * inv;
                    }
                }
            }
        }
    }
}

// ---------------- fallback: round-1 fused kernel ----------------
__global__ __launch_bounds__(256, 1) void edgeatt_kernel(
    const float* __restrict__ nf, const float* __restrict__ Wf,
    const __bf16* __restrict__ wbf, const int* __restrict__ tlenp,
    float* __restrict__ out, int use_wb)
{
    __shared__ __bf16 A_lds[A_ROWS * A_STRIDE];
    __shared__ __bf16 C_lds[A_ROWS * C_STRIDE];

    const int b = blockIdx.x;
    const int tid = threadIdx.x;
    const int lane = tid & 63;
    const int wave = tid >> 6;
    const int l15 = lane & 15;
    const int quad = lane >> 4;

    int len = tlenp[b];
    if (len > L_SZ) len = L_SZ;
    if (len < 1) len = 1;
    const int T = (len + 15) >> 4;

    const float* nfb = nf + (size_t)b * (L_SZ * D_SZ);
    float* outb = out + (size_t)b * (L_SZ * OUT_W);

    {
        int total4 = len * (D_SZ / 4);
        for (int idx = tid; idx < total4; idx += 256) {
            int row = idx >> 7;
            int c4 = idx & 127;
            float4 v = ((const float4*)nfb)[row * 128 + c4];
            bf16x4 o;
            o[0]=(__bf16)v.x; o[1]=(__bf16)v.y; o[2]=(__bf16)v.z; o[3]=(__bf16)v.w;
            *(bf16x4*)&A_lds[row * A_STRIDE + c4 * 4] = o;
        }
        int zr = 16 * T - len;
        if (zr > 0) {
            int per = A_STRIDE / 4;
            int totalz = zr * per;
            for (int idx = tid; idx < totalz; idx += 256) {
                int row = len + idx / per;
                int c4 = idx % per;
                bf16x4 z; z[0]=z[1]=z[2]=z[3]=(__bf16)0.0f;
                *(bf16x4*)&A_lds[row * A_STRIDE + c4 * 4] = z;
            }
        }
    }
    __syncthreads();

    const int wm = wave >> 1, wn = wave & 1;
    const int h = (T + 1) >> 1;
    const int mt_lo = (wm == 0) ? 0 : h;
    const int nmt = ((wm == 0) ? h : T) - mt_lo;

    const f32x4 fzero = {0.f, 0.f, 0.f, 0.f};
    f32x4 accS[2][3];
    #pragma unroll
    for (int i = 0; i < 2; ++i)
        #pragma unroll
        for (int t = 0; t < 3; ++t) accS[i][t] = fzero;

    for (int c = 0; c < 4; ++c) {
        const int d0 = c * 128;
        f32x4 acc1[4][4];
        #pragma unroll
        for (int mi = 0; mi < 4; ++mi)
            #pragma unroll
            for (int ni = 0; ni < 4; ++ni) acc1[mi][ni] = fzero;

        if (nmt > 0) {
            for (int k0 = 0; k0 < D_SZ; k0 += 32) {
                bf16x8 afrag[4], bfrag[4];
                #pragma unroll
                for (int ni = 0; ni < 4; ++ni) {
                    int d = d0 + (wn * 4 + ni) * 16 + l15;
                    if (use_wb) {
                        bfrag[ni] = *(const bf16x8*)&wbf[(size_t)d * D_SZ + k0 + quad * 8];
                    } else {
                        const float* wp = &Wf[(size_t)d * D_SZ + k0 + quad * 8];
                        float4 w0 = *(const float4*)wp;
                        float4 w1 = *(const float4*)(wp + 4);
                        bf16x8 bb;
                        bb[0]=(__bf16)w0.x; bb[1]=(__bf16)w0.y; bb[2]=(__bf16)w0.z; bb[3]=(__bf16)w0.w;
                        bb[4]=(__bf16)w1.x; bb[5]=(__bf16)w1.y; bb[6]=(__bf16)w1.z; bb[7]=(__bf16)w1.w;
                        bfrag[ni] = bb;
                    }
                }
                #pragma unroll
                for (int mi = 0; mi < 4; ++mi) {
                    if (mi < nmt) {
                        int row = (mt_lo + mi) * 16 + l15;
                        afrag[mi] = *(const bf16x8*)&A_lds[row * A_STRIDE + k0 + quad * 8];
                    }
                }
                #pragma unroll
                for (int mi = 0; mi < 4; ++mi) {
                    if (mi < nmt) {
                        #pragma unroll
                        for (int ni = 0; ni < 4; ++ni)
                            acc1[mi][ni] = __builtin_amdgcn_mfma_f32_16x16x32_bf16(
                                afrag[mi], bfrag[ni], acc1[mi][ni], 0, 0, 0);
                    }
                }
            }
        }
        __syncthreads();

        #pragma unroll
        for (int mi = 0; mi < 4; ++mi) {
            if (mi < nmt) {
                int lbase = (mt_lo + mi) * 16 + quad * 4;
                #pragma unroll
                for (int ni = 0; ni < 4; ++ni) {
                    int dloc = (wn * 4 + ni) * 16 + l15;
                    #pragma unroll
                    for (int r = 0; r < 4; ++r)
                        C_lds[(lbase + r) * C_STRIDE + dloc] = (__bf16)acc1[mi][ni][r];
                }
            }
        }
        __syncthreads();

        for (int kk = 0; kk < 128; kk += 32) {
            #pragma unroll
            for (int i = 0; i < 2; ++i) {
                int tj = wave + 4 * i;
                if (tj < T) {
                    bf16x8 aj = *(const bf16x8*)&A_lds[(tj * 16 + l15) * A_STRIDE + d0 + kk + quad * 8];
                    #pragma unroll
                    for (int t = 0; t < 3; ++t) {
                        int tl = tj - 1 + t;
                        if (tl >= 0 && tl < T) {
                            bf16x8 bj = *(const bf16x8*)&C_lds[(tl * 16 + l15) * C_STRIDE + kk + quad * 8];
                            accS[i][t] = __builtin_amdgcn_mfma_f32_16x16x32_bf16(
                                aj, bj, accS[i][t], 0, 0, 0);
                        }
                    }
                }
            }
        }
        __syncthreads();
    }

    #pragma unroll
    for (int i = 0; i < 2; ++i) {
        int tj = wave + 4 * i;
        if (tj >= T) continue;
        #pragma unroll
        for (int r = 0; r < 4; ++r) {
            int j = tj * 16 + quad * 4 + r;
            float v[3]; bool mk[3];
            float vmax = -3.0e38f;
            #pragma unroll
            for (int t = 0; t < 3; ++t) {
                int tl = tj - 1 + t;
                int l = tl * 16 + l15;
                bool in = (tl >= 0) && (tl < T) && (j < len) && (l < len)
                          && (l >= j - 10) && (l <= j + 10);
                float val = in ? accS[i][t][r] : -3.0e38f;
                mk[t] = in; v[t] = val;
                vmax = fmaxf(vmax, val);
            }
            #pragma unroll
            for (int s = 1; s < 16; s <<= 1)
                vmax = fmaxf(vmax, __shfl_xor(vmax, s, 16));
            float e[3]; float esum = 0.f;
            #pragma unroll
            for (int t = 0; t < 3; ++t) {
                e[t] = mk[t] ? __expf(v[t] - vmax) : 0.f;
                esum += e[t];
            }
            #pragma unroll
            for (int s = 1; s < 16; s <<= 1)
                esum += __shfl_xor(esum, s, 16);
            float inv = (esum > 0.f) ? (1.0f / esum) : 0.f;
            if (j < OUT_W) {
                #pragma unroll
                for (int t = 0; t < 3; ++t) {
                    int tl = tj - 1 + t;
                    if (tl >= 0 && tl < T) {
                        int l = tl * 16 + l15;
                        if (l < OUT_W) outb[(size_t)j * OUT_W + l] = e[t] * inv;
                    }
                }
            }
        }
    }
}

extern "C" void kernel_launch(void* const* d_in, const int* in_sizes, int n_in,
                              void* d_out, int out_size, void* d_ws, size_t ws_size,
                              hipStream_t stream) {
    const float* nf = (const float*)d_in[0];
    const float* W  = (const float*)d_in[1];
    const int* tl   = (const int*)d_in[2];
    float* out      = (float*)d_out;
    __bf16* wbf     = (__bf16*)d_ws;
    const int B = in_sizes[2];

    const size_t wb_bytes  = (size_t)D_SZ * D_SZ * sizeof(__bf16);
    const size_t att_bytes = (size_t)B * ATT_ROWS * D_SZ * sizeof(__bf16);
    const int use_wb = (ws_size >= wb_bytes) ? 1 : 0;
    const int fast   = (use_wb && ws_size >= wb_bytes + att_bytes) ? 1 : 0;

    // zero the whole output once; kernels only write the band region
    hipMemsetAsync(d_out, 0, (size_t)out_size * sizeof(float), stream);

    if (use_wb) {
        hipLaunchKernelGGL(wconv_kernel, dim3(256), dim3(256), 0, stream, W, wbf);
    }
    if (fast) {
        __bf16* attws = (__bf16*)((char*)d_ws + wb_bytes);
        hipLaunchKernelGGL(att_gemm2_kernel, dim3(4, B), dim3(256), 0, stream, nf, wbf, tl, attws);
        hipLaunchKernelGGL(band_kernel, dim3(B), dim3(256), 0, stream, nf, attws, tl, out);
    } else {
        hipLaunchKernelGGL(edgeatt_kernel, dim3(B), dim3(256), 0, stream,
                           nf, W, wbf, tl, out, use_wb);
    }
}

// Round 4
// 447.293 us; speedup vs baseline: 2.8870x; 2.8870x over previous
//
#include <hip/hip_runtime.h>
#include <stdint.h>

#define L_SZ 110
#define D_SZ 512
#define OUT_W 110
#define A_STRIDE 520   // fallback kernel LDS strides
#define C_STRIDE 136
#define A_ROWS 112
#define ATT_ROWS 112
#define G3_ST 40       // K1 LDS row stride in bf16 elems (32 + 8 pad -> uniform banks)

typedef __attribute__((ext_vector_type(8))) __bf16 bf16x8;
typedef __attribute__((ext_vector_type(4))) __bf16 bf16x4;
typedef __attribute__((ext_vector_type(4))) float f32x4;

// Convert W (512x512 fp32, row-major [d][e]) to bf16 in workspace.
__global__ __launch_bounds__(256) void wconv_kernel(const float* __restrict__ W,
                                                    __bf16* __restrict__ wbf) {
    int idx = blockIdx.x * 256 + threadIdx.x;
    float4 w = ((const float4*)W)[idx];
    bf16x4 o;
    o[0] = (__bf16)w.x; o[1] = (__bf16)w.y; o[2] = (__bf16)w.z; o[3] = (__bf16)w.w;
    ((bf16x4*)wbf)[idx] = o;
}

// ---------------- K1: att[b,l,d] = sum_e W[d,e]*nf[b,l,e] ----------------
// Block = (cg, b): BM=112 (m-tiles gated by T), BN=128, BK=32. 4 waves, wave
// tile 112x32. LDS-staged A (fp32->bf16) and B (bf16 W), 19.2 KB, 3 blocks/CU.
__global__ __launch_bounds__(256, 3) void att_gemm3_kernel(
    const float* __restrict__ nf, const __bf16* __restrict__ wbf,
    const int* __restrict__ tlenp, __bf16* __restrict__ attws)
{
    __shared__ __bf16 A_lds[112 * G3_ST];   // 8960 B
    __shared__ __bf16 B_lds[128 * G3_ST];   // 10240 B

    const int b   = blockIdx.y;
    const int cg  = blockIdx.x;             // 0..3, 128 cols each
    const int tid = threadIdx.x;
    const int lane = tid & 63;
    const int wave = tid >> 6;
    const int l15  = lane & 15;
    const int quad = lane >> 4;

    int len = tlenp[b];
    if (len > L_SZ) len = L_SZ;
    if (len < 1) len = 1;
    const int T = (len + 15) >> 4;
    const int rows_needed = T << 4;         // <= 112

    const float* nfb = nf + (size_t)b * (L_SZ * D_SZ);

    // staging map: thread covers rows r0 and r0+64 at col chunk c8 (8 elems)
    const int r0 = tid >> 2;
    const int c8 = (tid & 3) << 3;
    const int rows2[2] = { r0, r0 + 64 };
    int stat[2];                             // 0=skip, 1=load, 2=zero
    #pragma unroll
    for (int s = 0; s < 2; ++s) {
        int r = rows2[s];
        stat[s] = (r >= rows_needed) ? 0 : ((r < L_SZ) ? 1 : 2);
    }

    f32x4 acc[7][2];
    const f32x4 fz = {0.f, 0.f, 0.f, 0.f};
    #pragma unroll
    for (int m = 0; m < 7; ++m) { acc[m][0] = fz; acc[m][1] = fz; }

    float4 abuf[2][2];
    bf16x8 bbuf[2];

    auto load_tiles = [&](int k0) {
        #pragma unroll
        for (int s = 0; s < 2; ++s) {
            if (stat[s] == 1) {
                const float* ap = nfb + (size_t)rows2[s] * D_SZ + k0 + c8;
                abuf[s][0] = *(const float4*)ap;
                abuf[s][1] = *(const float4*)(ap + 4);
            }
            bbuf[s] = *(const bf16x8*)&wbf[(size_t)(cg * 128 + rows2[s]) * D_SZ + k0 + c8];
        }
    };
    auto store_tiles = [&]() {
        #pragma unroll
        for (int s = 0; s < 2; ++s) {
            if (stat[s]) {
                bf16x8 o;
                if (stat[s] == 1) {
                    o[0]=(__bf16)abuf[s][0].x; o[1]=(__bf16)abuf[s][0].y;
                    o[2]=(__bf16)abuf[s][0].z; o[3]=(__bf16)abuf[s][0].w;
                    o[4]=(__bf16)abuf[s][1].x; o[5]=(__bf16)abuf[s][1].y;
                    o[6]=(__bf16)abuf[s][1].z; o[7]=(__bf16)abuf[s][1].w;
                } else {
                    o[0]=o[1]=o[2]=o[3]=o[4]=o[5]=o[6]=o[7]=(__bf16)0.0f;
                }
                *(bf16x8*)&A_lds[rows2[s] * G3_ST + c8] = o;
            }
            *(bf16x8*)&B_lds[rows2[s] * G3_ST + c8] = bbuf[s];
        }
    };

    load_tiles(0);
    for (int kt = 0; kt < 16; ++kt) {
        store_tiles();
        __syncthreads();
        if (kt < 15) load_tiles((kt + 1) << 5);   // fly under the MFMAs below
        bf16x8 bfr[2];
        #pragma unroll
        for (int ni = 0; ni < 2; ++ni)
            bfr[ni] = *(const bf16x8*)&B_lds[(wave * 32 + ni * 16 + l15) * G3_ST + quad * 8];
        #pragma unroll
        for (int m = 0; m < 7; ++m) {
            if (m < T) {                           // wave-uniform gate
                bf16x8 af = *(const bf16x8*)&A_lds[(m * 16 + l15) * G3_ST + quad * 8];
                acc[m][0] = __builtin_amdgcn_mfma_f32_16x16x32_bf16(af, bfr[0], acc[m][0], 0, 0, 0);
                acc[m][1] = __builtin_amdgcn_mfma_f32_16x16x32_bf16(af, bfr[1], acc[m][1], 0, 0, 0);
            }
        }
        __syncthreads();
    }

    // epilogue: wave-private LDS transpose (C/D layout -> row-major), 16B stores
    __bf16* tw = &A_lds[wave * 16 * G3_ST];
    const size_t obase = (size_t)b * (ATT_ROWS * D_SZ) + cg * 128 + wave * 32;
    const int erow = lane >> 2;
    const int ec8  = (lane & 3) << 3;
    #pragma unroll
    for (int m = 0; m < 7; ++m) {
        if (m < T) {
            #pragma unroll
            for (int ni = 0; ni < 2; ++ni)
                #pragma unroll
                for (int r = 0; r < 4; ++r)
                    tw[(quad * 4 + r) * G3_ST + ni * 16 + l15] = (__bf16)acc[m][ni][r];
            bf16x8 v = *(const bf16x8*)&tw[erow * G3_ST + ec8];
            *(bf16x8*)&attws[obase + (size_t)(m * 16 + erow) * D_SZ + ec8] = v;
        }
    }
}

// ---------------- K2: banded scores + masked softmax, no LDS, no barriers ----------------
__global__ __launch_bounds__(256) void band_kernel(
    const float* __restrict__ nf, const __bf16* __restrict__ attws,
    const int* __restrict__ tlenp, float* __restrict__ out)
{
    const int b = blockIdx.x;
    const int tid = threadIdx.x;
    const int lane = tid & 63;
    const int wave = tid >> 6;
    const int l15 = lane & 15;
    const int quad = lane >> 4;

    int len = tlenp[b];
    if (len > L_SZ) len = L_SZ;
    if (len < 1) len = 1;
    const int T = (len + 15) >> 4;

    const float* nfb = nf + (size_t)b * (L_SZ * D_SZ);
    float* outb = out + (size_t)b * (L_SZ * OUT_W);

    const f32x4 fz = {0.f, 0.f, 0.f, 0.f};
    f32x4 accS[2][3];
    #pragma unroll
    for (int i = 0; i < 2; ++i)
        #pragma unroll
        for (int t = 0; t < 3; ++t) accS[i][t] = fz;

    #pragma unroll
    for (int i = 0; i < 2; ++i) {
        const int tj = wave + (i << 2);
        if (tj < T) {
            int jr = (tj << 4) + l15;
            if (jr > L_SZ - 1) jr = L_SZ - 1;   // in-bounds; rows >= len masked later
            const float* ap0 = &nfb[(size_t)jr * D_SZ];
            for (int k0 = 0; k0 < D_SZ; k0 += 32) {
                float4 a0 = *(const float4*)(ap0 + k0 + (quad << 3));
                float4 a1 = *(const float4*)(ap0 + k0 + (quad << 3) + 4);
                bf16x8 af;
                af[0] = (__bf16)a0.x; af[1] = (__bf16)a0.y;
                af[2] = (__bf16)a0.z; af[3] = (__bf16)a0.w;
                af[4] = (__bf16)a1.x; af[5] = (__bf16)a1.y;
                af[6] = (__bf16)a1.z; af[7] = (__bf16)a1.w;
                #pragma unroll
                for (int t = 0; t < 3; ++t) {
                    int tl = tj - 1 + t;
                    if (tl >= 0 && tl < T) {
                        bf16x8 bfr = *(const bf16x8*)&attws[((size_t)b * ATT_ROWS + (tl << 4) + l15) * D_SZ + k0 + (quad << 3)];
                        accS[i][t] = __builtin_amdgcn_mfma_f32_16x16x32_bf16(
                            af, bfr, accS[i][t], 0, 0, 0);
                    }
                }
            }
        }
    }

    #pragma unroll
    for (int i = 0; i < 2; ++i) {
        int tj = wave + 4 * i;
        if (tj >= T) continue;           // wave-uniform
        #pragma unroll
        for (int r = 0; r < 4; ++r) {
            int j = tj * 16 + quad * 4 + r;
            float v[3]; bool mk[3];
            float vmax = -3.0e38f;
            #pragma unroll
            for (int t = 0; t < 3; ++t) {
                int tl = tj - 1 + t;
                int l = tl * 16 + l15;
                bool in = (tl >= 0) && (tl < T) && (j < len) && (l < len)
                          && (l >= j - 10) && (l <= j + 10);
                float val = in ? accS[i][t][r] : -3.0e38f;
                mk[t] = in; v[t] = val;
                vmax = fmaxf(vmax, val);
            }
            #pragma unroll
            for (int s = 1; s < 16; s <<= 1)
                vmax = fmaxf(vmax, __shfl_xor(vmax, s, 16));
            float e[3]; float esum = 0.f;
            #pragma unroll
            for (int t = 0; t < 3; ++t) {
                e[t] = mk[t] ? __expf(v[t] - vmax) : 0.f;
                esum += e[t];
            }
            #pragma unroll
            for (int s = 1; s < 16; s <<= 1)
                esum += __shfl_xor(esum, s, 16);
            float inv = (esum > 0.f) ? (1.0f / esum) : 0.f;
            if (j < OUT_W) {
                #pragma unroll
                for (int t = 0; t < 3; ++t) {
                    int tl = tj - 1 + t;
                    if (tl >= 0 && tl < T) {
                        int l = tl * 16 + l15;
                        if (l < OUT_W) outb[(size_t)j * OUT_W + l] = e[t] * inv;
                    }
                }
            }
        }
    }
}

// ---------------- fallback: round-1 fused kernel ----------------
__global__ __launch_bounds__(256, 1) void edgeatt_kernel(
    const float* __restrict__ nf, const float* __restrict__ Wf,
    const __bf16* __restrict__ wbf, const int* __restrict__ tlenp,
    float* __restrict__ out, int use_wb)
{
    __shared__ __bf16 A_lds[A_ROWS * A_STRIDE];
    __shared__ __bf16 C_lds[A_ROWS * C_STRIDE];

    const int b = blockIdx.x;
    const int tid = threadIdx.x;
    const int lane = tid & 63;
    const int wave = tid >> 6;
    const int l15 = lane & 15;
    const int quad = lane >> 4;

    int len = tlenp[b];
    if (len > L_SZ) len = L_SZ;
    if (len < 1) len = 1;
    const int T = (len + 15) >> 4;

    const float* nfb = nf + (size_t)b * (L_SZ * D_SZ);
    float* outb = out + (size_t)b * (L_SZ * OUT_W);

    {
        int total4 = len * (D_SZ / 4);
        for (int idx = tid; idx < total4; idx += 256) {
            int row = idx >> 7;
            int c4 = idx & 127;
            float4 v = ((const float4*)nfb)[row * 128 + c4];
            bf16x4 o;
            o[0]=(__bf16)v.x; o[1]=(__bf16)v.y; o[2]=(__bf16)v.z; o[3]=(__bf16)v.w;
            *(bf16x4*)&A_lds[row * A_STRIDE + c4 * 4] = o;
        }
        int zr = 16 * T - len;
        if (zr > 0) {
            int per = A_STRIDE / 4;
            int totalz = zr * per;
            for (int idx = tid; idx < totalz; idx += 256) {
                int row = len + idx / per;
                int c4 = idx % per;
                bf16x4 z; z[0]=z[1]=z[2]=z[3]=(__bf16)0.0f;
                *(bf16x4*)&A_lds[row * A_STRIDE + c4 * 4] = z;
            }
        }
    }
    __syncthreads();

    const int wm = wave >> 1, wn = wave & 1;
    const int h = (T + 1) >> 1;
    const int mt_lo = (wm == 0) ? 0 : h;
    const int nmt = ((wm == 0) ? h : T) - mt_lo;

    const f32x4 fzero = {0.f, 0.f, 0.f, 0.f};
    f32x4 accS[2][3];
    #pragma unroll
    for (int i = 0; i < 2; ++i)
        #pragma unroll
        for (int t = 0; t < 3; ++t) accS[i][t] = fzero;

    for (int c = 0; c < 4; ++c) {
        const int d0 = c * 128;
        f32x4 acc1[4][4];
        #pragma unroll
        for (int mi = 0; mi < 4; ++mi)
            #pragma unroll
            for (int ni = 0; ni < 4; ++ni) acc1[mi][ni] = fzero;

        if (nmt > 0) {
            for (int k0 = 0; k0 < D_SZ; k0 += 32) {
                bf16x8 afrag[4], bfrag[4];
                #pragma unroll
                for (int ni = 0; ni < 4; ++ni) {
                    int d = d0 + (wn * 4 + ni) * 16 + l15;
                    if (use_wb) {
                        bfrag[ni] = *(const bf16x8*)&wbf[(size_t)d * D_SZ + k0 + quad * 8];
                    } else {
                        const float* wp = &Wf[(size_t)d * D_SZ + k0 + quad * 8];
                        float4 w0 = *(const float4*)wp;
                        float4 w1 = *(const float4*)(wp + 4);
                        bf16x8 bb;
                        bb[0]=(__bf16)w0.x; bb[1]=(__bf16)w0.y; bb[2]=(__bf16)w0.z; bb[3]=(__bf16)w0.w;
                        bb[4]=(__bf16)w1.x; bb[5]=(__bf16)w1.y; bb[6]=(__bf16)w1.z; bb[7]=(__bf16)w1.w;
                        bfrag[ni] = bb;
                    }
                }
                #pragma unroll
                for (int mi = 0; mi < 4; ++mi) {
                    if (mi < nmt) {
                        int row = (mt_lo + mi) * 16 + l15;
                        afrag[mi] = *(const bf16x8*)&A_lds[row * A_STRIDE + k0 + quad * 8];
                    }
                }
                #pragma unroll
                for (int mi = 0; mi < 4; ++mi) {
                    if (mi < nmt) {
                        #pragma unroll
                        for (int ni = 0; ni < 4; ++ni)
                            acc1[mi][ni] = __builtin_amdgcn_mfma_f32_16x16x32_bf16(
                                afrag[mi], bfrag[ni], acc1[mi][ni], 0, 0, 0);
                    }
                }
            }
        }
        __syncthreads();

        #pragma unroll
        for (int mi = 0; mi < 4; ++mi) {
            if (mi < nmt) {
                int lbase = (mt_lo + mi) * 16 + quad * 4;
                #pragma unroll
                for (int ni = 0; ni < 4; ++ni) {
                    int dloc = (wn * 4 + ni) * 16 + l15;
                    #pragma unroll
                    for (int r = 0; r < 4; ++r)
                        C_lds[(lbase + r) * C_STRIDE + dloc] = (__bf16)acc1[mi][ni][r];
                }
            }
        }
        __syncthreads();

        for (int kk = 0; kk < 128; kk += 32) {
            #pragma unroll
            for (int i = 0; i < 2; ++i) {
                int tj = wave + 4 * i;
                if (tj < T) {
                    bf16x8 aj = *(const bf16x8*)&A_lds[(tj * 16 + l15) * A_STRIDE + d0 + kk + quad * 8];
                    #pragma unroll
                    for (int t = 0; t < 3; ++t) {
                        int tl = tj - 1 + t;
                        if (tl >= 0 && tl < T) {
                            bf16x8 bj = *(const bf16x8*)&C_lds[(tl * 16 + l15) * C_STRIDE + kk + quad * 8];
                            accS[i][t] = __builtin_amdgcn_mfma_f32_16x16x32_bf16(
                                aj, bj, accS[i][t], 0, 0, 0);
                        }
                    }
                }
            }
        }
        __syncthreads();
    }

    #pragma unroll
    for (int i = 0; i < 2; ++i) {
        int tj = wave + 4 * i;
        if (tj >= T) continue;
        #pragma unroll
        for (int r = 0; r < 4; ++r) {
            int j = tj * 16 + quad * 4 + r;
            float v[3]; bool mk[3];
            float vmax = -3.0e38f;
            #pragma unroll
            for (int t = 0; t < 3; ++t) {
                int tl = tj - 1 + t;
                int l = tl * 16 + l15;
                bool in = (tl >= 0) && (tl < T) && (j < len) && (l < len)
                          && (l >= j - 10) && (l <= j + 10);
                float val = in ? accS[i][t][r] : -3.0e38f;
                mk[t] = in; v[t] = val;
                vmax = fmaxf(vmax, val);
            }
            #pragma unroll
            for (int s = 1; s < 16; s <<= 1)
                vmax = fmaxf(vmax, __shfl_xor(vmax, s, 16));
            float e[3]; float esum = 0.f;
            #pragma unroll
            for (int t = 0; t < 3; ++t) {
                e[t] = mk[t] ? __expf(v[t] - vmax) : 0.f;
                esum += e[t];
            }
            #pragma unroll
            for (int s = 1; s < 16; s <<= 1)
                esum += __shfl_xor(esum, s, 16);
            float inv = (esum > 0.f) ? (1.0f / esum) : 0.f;
            if (j < OUT_W) {
                #pragma unroll
                for (int t = 0; t < 3; ++t) {
                    int tl = tj - 1 + t;
                    if (tl >= 0 && tl < T) {
                        int l = tl * 16 + l15;
                        if (l < OUT_W) outb[(size_t)j * OUT_W + l] = e[t] * inv;
                    }
                }
            }
        }
    }
}

extern "C" void kernel_launch(void* const* d_in, const int* in_sizes, int n_in,
                              void* d_out, int out_size, void* d_ws, size_t ws_size,
                              hipStream_t stream) {
    const float* nf = (const float*)d_in[0];
    const float* W  = (const float*)d_in[1];
    const int* tl   = (const int*)d_in[2];
    float* out      = (float*)d_out;
    __bf16* wbf     = (__bf16*)d_ws;
    const int B = in_sizes[2];

    const size_t wb_bytes  = (size_t)D_SZ * D_SZ * sizeof(__bf16);
    const size_t att_bytes = (size_t)B * ATT_ROWS * D_SZ * sizeof(__bf16);
    const int use_wb = (ws_size >= wb_bytes) ? 1 : 0;
    const int fast   = (use_wb && ws_size >= wb_bytes + att_bytes) ? 1 : 0;

    // zero the whole output once; kernels only write the band region
    hipMemsetAsync(d_out, 0, (size_t)out_size * sizeof(float), stream);

    if (use_wb) {
        hipLaunchKernelGGL(wconv_kernel, dim3(256), dim3(256), 0, stream, W, wbf);
    }
    if (fast) {
        __bf16* attws = (__bf16*)((char*)d_ws + wb_bytes);
        hipLaunchKernelGGL(att_gemm3_kernel, dim3(4, B), dim3(256), 0, stream, nf, wbf, tl, attws);
        hipLaunchKernelGGL(band_kernel, dim3(B), dim3(256), 0, stream, nf, attws, tl, out);
    } else {
        hipLaunchKernelGGL(edgeatt_kernel, dim3(B), dim3(256), 0, stream,
                           nf, W, wbf, tl, out, use_wb);
    }
}